// Round 7
// baseline (112.047 us; speedup 1.0000x reference)
//
#include <hip/hip_runtime.h>
#include <hip/hip_bf16.h>

#define IN_F 8192
#define OUT_F 8192
#define NROWS 128
#define CB 256
#define NSL 8                  // split-K slices
#define KSLICE (IN_F / NSL)    // 1024
#define NTB 64                 // n-tile per block

using bf8   = __attribute__((ext_vector_type(8))) short;  // 8 bf16 (4 VGPRs)
using f32x4 = __attribute__((ext_vector_type(4))) float;  // 4 fp32 accum

__device__ inline float bf2f(unsigned int u) {
    union { unsigned int i; float f; } v; v.i = u << 16; return v.f;
}
__device__ inline unsigned short f2bf(float f) {
    __hip_bfloat16 h = __float2bfloat16(f);
    return *reinterpret_cast<unsigned short*>(&h);
}
__device__ inline void unpack8(uint4 v, float* f) {
    f[0] = bf2f(v.x & 0xffffu); f[1] = bf2f(v.x >> 16);
    f[2] = bf2f(v.y & 0xffffu); f[3] = bf2f(v.y >> 16);
    f[4] = bf2f(v.z & 0xffffu); f[5] = bf2f(v.z >> 16);
    f[6] = bf2f(v.w & 0xffffu); f[7] = bf2f(v.w >> 16);
}

#define FWHT_SCALE 0.011048543456039806f  // 1/sqrt(8192)

// 3-level in-register FWHT-8192: 256 threads x 32 elems. (round-5 proven)
#define FWHT_STAGES(LOJ, HIJ)                                             \
    _Pragma("unroll")                                                     \
    for (int hb = (LOJ); hb < (HIJ); ++hb) {                              \
        const int h = 1 << hb;                                            \
        _Pragma("unroll")                                                 \
        for (int j = 0; j < 32; ++j)                                      \
            if (!(j & h)) {                                               \
                float a = v[j], b = v[j | h];                             \
                v[j] = a + b; v[j | h] = a - b;                           \
            }                                                             \
    }

__device__ inline void fwht8192(float* v, float* lds, int t) {
    FWHT_STAGES(0, 5)
#pragma unroll
    for (int j = 0; j < 32; ++j) lds[j * 257 + t] = v[j];
    __syncthreads();
    {
        const int o = t & 31, uh = t >> 5;
        const int base = o * 257 + uh * 32;
#pragma unroll
        for (int k = 0; k < 32; ++k) v[k] = lds[base + k];
    }
    FWHT_STAGES(0, 4)
    __syncthreads();
    {
        const int o = t & 31, uh = t >> 5;
#pragma unroll
        for (int k = 0; k < 32; ++k)
            lds[o * 257 + (k & 15) * 16 + uh * 2 + (k >> 4)] = v[k];
    }
    __syncthreads();
    {
        const int o = t & 31, mh = t >> 5;
#pragma unroll
        for (int h2 = 0; h2 < 2; ++h2)
#pragma unroll
            for (int w = 0; w < 16; ++w)
                v[h2 * 16 + w] = lds[o * 257 + (mh * 2 + h2) * 16 + w];
    }
    FWHT_STAGES(0, 4)
    __syncthreads();
    {
        const int o = t & 31, mh = t >> 5;
#pragma unroll
        for (int h2 = 0; h2 < 2; ++h2) {
            const int M = 2 * mh + h2;
#pragma unroll
            for (int w = 0; w < 16; ++w) {
                const int i = w * 512 + M * 32 + o;
                const int q2 = (i >> 2) ^ (M & 7);
                lds[q2 * 4 + (o & 3)] = v[h2 * 16 + w];
            }
        }
    }
    __syncthreads();
#pragma unroll
    for (int j4 = 0; j4 < 8; ++j4) {
        const int q2 = (t * 8 + j4) ^ (t & 7);
        const float4 f = *reinterpret_cast<const float4*>(&lds[q2 * 4]);
        v[j4 * 4 + 0] = f.x; v[j4 * 4 + 1] = f.y;
        v[j4 * 4 + 2] = f.z; v[j4 * 4 + 3] = f.w;
    }
}

// ---- Kernel A: xpre = fwht(input/scaleWH*SU)  [bf16 out] ----
__global__ __launch_bounds__(256) void k_pre2(const float* __restrict__ in,
                                              const float* __restrict__ scaleWH,
                                              const float* __restrict__ SU,
                                              unsigned short* __restrict__ xpre) {
    __shared__ float lds[8224];
    const int r = blockIdx.x, t = threadIdx.x;
    float v[32];
    const float4* xp = reinterpret_cast<const float4*>(in + (size_t)r * IN_F);
    const float4* sp = reinterpret_cast<const float4*>(scaleWH);
    const float4* up = reinterpret_cast<const float4*>(SU);
#pragma unroll
    for (int q = 0; q < 8; ++q) {
        float4 x = xp[t * 8 + q], s = sp[t * 8 + q], u = up[t * 8 + q];
        v[q * 4 + 0] = x.x / s.x * u.x;
        v[q * 4 + 1] = x.y / s.y * u.y;
        v[q * 4 + 2] = x.z / s.z * u.z;
        v[q * 4 + 3] = x.w / s.w * u.w;
    }
    fwht8192(v, lds, t);
    uint4* dst = reinterpret_cast<uint4*>(xpre + (size_t)r * IN_F);
#pragma unroll
    for (int q = 0; q < 4; ++q) {
        unsigned int w[4];
#pragma unroll
        for (int p = 0; p < 4; ++p) {
            unsigned int lo = f2bf(v[q * 8 + 2 * p]     * FWHT_SCALE);
            unsigned int hi = f2bf(v[q * 8 + 2 * p + 1] * FWHT_SCALE);
            w[p] = lo | (hi << 16);
        }
        dst[t * 4 + q] = make_uint4(w[0], w[1], w[2], w[3]);
    }
}

// ---- Kernel B: barrier-free GEMM, A direct global->VGPR, B from codebook ---
// grid (128, NSL); 256 thr = 4 waves (2x2); block tile 128x64; K-step 32,
// register ping-pong (static indexing). LDS: 4KB codebook only.
__global__ __launch_bounds__(256, 4) void k_gemm3(
        const unsigned short* __restrict__ xpre,
        const int* __restrict__ Qidxs,
        const float* __restrict__ cb,
        const float* __restrict__ wscale,
        unsigned short* __restrict__ pout) {
    __shared__ __align__(16) unsigned short cbl[CB][8];
    const int tid = threadIdx.x;
    const int wave = tid >> 6, lane = tid & 63;
    const int wr = wave >> 1, wc = wave & 1;
    const int lr = lane & 15, lk8 = lane >> 4;
    const int n0 = blockIdx.x * NTB;
    const int ks0 = blockIdx.y * KSLICE;
    const int QC = IN_F / 8;

    const float wsc = wscale[0];
    for (int e = tid; e < CB * 8; e += 256) cbl[e >> 3][e & 7] = f2bf(cb[e] * wsc);

    f32x4 acc[4][2];
#pragma unroll
    for (int mt = 0; mt < 4; ++mt)
#pragma unroll
        for (int nt = 0; nt < 2; ++nt) acc[mt][nt] = (f32x4){0.f, 0.f, 0.f, 0.f};

    // per-lane A row pointers (row = wr*64 + mt*16 + lr), k = ks0 + it*32 + lk8*8
    const unsigned short* ap0 = xpre + (size_t)(wr * 64 +  0 + lr) * IN_F + ks0 + lk8 * 8;
    const unsigned short* ap1 = xpre + (size_t)(wr * 64 + 16 + lr) * IN_F + ks0 + lk8 * 8;
    const unsigned short* ap2 = xpre + (size_t)(wr * 64 + 32 + lr) * IN_F + ks0 + lk8 * 8;
    const unsigned short* ap3 = xpre + (size_t)(wr * 64 + 48 + lr) * IN_F + ks0 + lk8 * 8;
    const int* q0 = Qidxs + (size_t)(n0 + wc * 32 + lr) * QC + ks0 / 8;

#define LOADA(dst, it)                                                        \
    {                                                                         \
        dst##0 = *reinterpret_cast<const bf8*>(ap0 + (it) * 32);              \
        dst##1 = *reinterpret_cast<const bf8*>(ap1 + (it) * 32);              \
        dst##2 = *reinterpret_cast<const bf8*>(ap2 + (it) * 32);              \
        dst##3 = *reinterpret_cast<const bf8*>(ap3 + (it) * 32);              \
    }
#define LOADI(d0, d1, it)                                                     \
    { d0 = q0[(it) * 4 + lk8]; d1 = q0[16 * QC + (it) * 4 + lk8]; }
#define COMPUTE(src, i0, i1)                                                  \
    {                                                                         \
        bf8 b0 = *(const bf8*)&cbl[i0][0];                                    \
        bf8 b1 = *(const bf8*)&cbl[i1][0];                                    \
        acc[0][0] = __builtin_amdgcn_mfma_f32_16x16x32_bf16(src##0, b0, acc[0][0], 0, 0, 0); \
        acc[0][1] = __builtin_amdgcn_mfma_f32_16x16x32_bf16(src##0, b1, acc[0][1], 0, 0, 0); \
        acc[1][0] = __builtin_amdgcn_mfma_f32_16x16x32_bf16(src##1, b0, acc[1][0], 0, 0, 0); \
        acc[1][1] = __builtin_amdgcn_mfma_f32_16x16x32_bf16(src##1, b1, acc[1][1], 0, 0, 0); \
        acc[2][0] = __builtin_amdgcn_mfma_f32_16x16x32_bf16(src##2, b0, acc[2][0], 0, 0, 0); \
        acc[2][1] = __builtin_amdgcn_mfma_f32_16x16x32_bf16(src##2, b1, acc[2][1], 0, 0, 0); \
        acc[3][0] = __builtin_amdgcn_mfma_f32_16x16x32_bf16(src##3, b0, acc[3][0], 0, 0, 0); \
        acc[3][1] = __builtin_amdgcn_mfma_f32_16x16x32_bf16(src##3, b1, acc[3][1], 0, 0, 0); \
    }

    bf8 aA0, aA1, aA2, aA3, aB0, aB1, aB2, aB3;
    int iA0, iA1, iB0, iB1;
    LOADA(aA, 0) LOADI(iA0, iA1, 0)
    __syncthreads();   // cbl ready

#pragma unroll 1
    for (int it = 0; it < KSLICE / 32; it += 2) {
        LOADA(aB, it + 1) LOADI(iB0, iB1, it + 1)
        COMPUTE(aA, iA0, iA1)
        if (it + 2 < KSLICE / 32) { LOADA(aA, it + 2) LOADI(iA0, iA1, it + 2) }
        COMPUTE(aB, iB0, iB1)
    }
#undef LOADA
#undef LOADI
#undef COMPUTE

    // epilogue: C/D col=lane&15, row=(lane>>4)*4+reg; bf16 partial store
    unsigned short* ps = pout + (size_t)blockIdx.y * (NROWS * OUT_F);
#pragma unroll
    for (int mt = 0; mt < 4; ++mt) {
        const int row = wr * 64 + mt * 16 + lk8 * 4;
#pragma unroll
        for (int nt = 0; nt < 2; ++nt) {
            const int col = n0 + wc * 32 + nt * 16 + lr;
#pragma unroll
            for (int r2 = 0; r2 < 4; ++r2)
                ps[(size_t)(row + r2) * OUT_F + col] = f2bf(acc[mt][nt][r2]);
        }
    }
}

// ---- Kernel C: out = fwht(sum_slices)*SV + bias  [f32 out] ----
__global__ __launch_bounds__(256) void k_post2(const unsigned short* __restrict__ pin,
                                               const float* __restrict__ SV,
                                               const float* __restrict__ bias,
                                               float* __restrict__ out) {
    __shared__ float lds[8224];
    const int r = blockIdx.x, t = threadIdx.x;
    float v[32];
#pragma unroll
    for (int j = 0; j < 32; ++j) v[j] = 0.f;
#pragma unroll 1
    for (int sl = 0; sl < NSL; ++sl) {
        const uint4* p = reinterpret_cast<const uint4*>(
            pin + (size_t)sl * NROWS * OUT_F + (size_t)r * OUT_F + t * 32);
#pragma unroll
        for (int q = 0; q < 4; ++q) {
            float a[8];
            unpack8(p[q], a);
#pragma unroll
            for (int j = 0; j < 8; ++j) v[q * 8 + j] += a[j];
        }
    }
    fwht8192(v, lds, t);
    const float4* svp = reinterpret_cast<const float4*>(SV);
    const float4* bip = reinterpret_cast<const float4*>(bias);
    float4* op = reinterpret_cast<float4*>(out + (size_t)r * OUT_F);
#pragma unroll
    for (int q = 0; q < 8; ++q) {
        float4 sv = svp[t * 8 + q], bi = bip[t * 8 + q], o;
        o.x = v[q * 4 + 0] * FWHT_SCALE * sv.x + bi.x;
        o.y = v[q * 4 + 1] * FWHT_SCALE * sv.y + bi.y;
        o.z = v[q * 4 + 2] * FWHT_SCALE * sv.z + bi.z;
        o.w = v[q * 4 + 3] * FWHT_SCALE * sv.w + bi.w;
        op[t * 8 + q] = o;
    }
}

extern "C" void kernel_launch(void* const* d_in, const int* in_sizes, int n_in,
                              void* d_out, int out_size, void* d_ws, size_t ws_size,
                              hipStream_t stream) {
    const float* in      = (const float*)d_in[0];
    const int*   Qidxs   = (const int*)d_in[1];
    const float* cb      = (const float*)d_in[2];
    const float* scaleWH = (const float*)d_in[3];
    const float* SU      = (const float*)d_in[4];
    const float* SV      = (const float*)d_in[5];
    const float* wscale  = (const float*)d_in[6];
    const float* bias    = (const float*)d_in[7];
    float* out = (float*)d_out;

    unsigned short* xpre  = (unsigned short*)d_ws;                    // 2 MB
    unsigned short* parts = (unsigned short*)((char*)d_ws
                            + (size_t)NROWS * IN_F * 2);              // 16 MB

    k_pre2<<<NROWS, 256, 0, stream>>>(in, scaleWH, SU, xpre);
    k_gemm3<<<dim3(OUT_F / NTB, NSL), 256, 0, stream>>>(xpre, Qidxs, cb, wscale, parts);
    k_post2<<<NROWS, 256, 0, stream>>>(parts, SV, bias, out);
}

// Round 8
// 72.569 us; speedup vs baseline: 1.5440x; 1.5440x over previous
//
#include <hip/hip_runtime.h>
#include <hip/hip_bf16.h>

#define IN_F 8192
#define OUT_F 8192
#define NROWS 128
#define CB 256
#define NSL 8                  // split-K slices
#define KSLICE (IN_F / NSL)    // 1024
#define NTB 64                 // n-tile per block
#define NIT (KSLICE / 32)      // 32 K-iterations per block

using bf8   = __attribute__((ext_vector_type(8))) short;  // 8 bf16 (4 VGPRs)
using f32x4 = __attribute__((ext_vector_type(4))) float;  // 4 fp32 accum

__device__ inline float bf2f(unsigned int u) {
    union { unsigned int i; float f; } v; v.i = u << 16; return v.f;
}
__device__ inline unsigned short f2bf(float f) {
    __hip_bfloat16 h = __float2bfloat16(f);
    return *reinterpret_cast<unsigned short*>(&h);
}
__device__ inline void unpack8(uint4 v, float* f) {
    f[0] = bf2f(v.x & 0xffffu); f[1] = bf2f(v.x >> 16);
    f[2] = bf2f(v.y & 0xffffu); f[3] = bf2f(v.y >> 16);
    f[4] = bf2f(v.z & 0xffffu); f[5] = bf2f(v.z >> 16);
    f[6] = bf2f(v.w & 0xffffu); f[7] = bf2f(v.w >> 16);
}

#define FWHT_SCALE 0.011048543456039806f  // 1/sqrt(8192)

// 3-level in-register FWHT-8192: 256 threads x 32 elems. (round-5 proven)
#define FWHT_STAGES(LOJ, HIJ)                                             \
    _Pragma("unroll")                                                     \
    for (int hb = (LOJ); hb < (HIJ); ++hb) {                              \
        const int h = 1 << hb;                                            \
        _Pragma("unroll")                                                 \
        for (int j = 0; j < 32; ++j)                                      \
            if (!(j & h)) {                                               \
                float a = v[j], b = v[j | h];                             \
                v[j] = a + b; v[j | h] = a - b;                           \
            }                                                             \
    }

__device__ inline void fwht8192(float* v, float* lds, int t) {
    FWHT_STAGES(0, 5)
#pragma unroll
    for (int j = 0; j < 32; ++j) lds[j * 257 + t] = v[j];
    __syncthreads();
    {
        const int o = t & 31, uh = t >> 5;
        const int base = o * 257 + uh * 32;
#pragma unroll
        for (int k = 0; k < 32; ++k) v[k] = lds[base + k];
    }
    FWHT_STAGES(0, 4)
    __syncthreads();
    {
        const int o = t & 31, uh = t >> 5;
#pragma unroll
        for (int k = 0; k < 32; ++k)
            lds[o * 257 + (k & 15) * 16 + uh * 2 + (k >> 4)] = v[k];
    }
    __syncthreads();
    {
        const int o = t & 31, mh = t >> 5;
#pragma unroll
        for (int h2 = 0; h2 < 2; ++h2)
#pragma unroll
            for (int w = 0; w < 16; ++w)
                v[h2 * 16 + w] = lds[o * 257 + (mh * 2 + h2) * 16 + w];
    }
    FWHT_STAGES(0, 4)
    __syncthreads();
    {
        const int o = t & 31, mh = t >> 5;
#pragma unroll
        for (int h2 = 0; h2 < 2; ++h2) {
            const int M = 2 * mh + h2;
#pragma unroll
            for (int w = 0; w < 16; ++w) {
                const int i = w * 512 + M * 32 + o;
                const int q2 = (i >> 2) ^ (M & 7);
                lds[q2 * 4 + (o & 3)] = v[h2 * 16 + w];
            }
        }
    }
    __syncthreads();
#pragma unroll
    for (int j4 = 0; j4 < 8; ++j4) {
        const int q2 = (t * 8 + j4) ^ (t & 7);
        const float4 f = *reinterpret_cast<const float4*>(&lds[q2 * 4]);
        v[j4 * 4 + 0] = f.x; v[j4 * 4 + 1] = f.y;
        v[j4 * 4 + 2] = f.z; v[j4 * 4 + 3] = f.w;
    }
}

// ---- Kernel A: xt = fwht(input/scaleWH*SU) in MFMA-tiled bf16 layout ----
// Tiled layout: elem (r,k) at ((r>>4)*256 + (k>>5))*512 + ((k&31)>>3)*128
//               + (r&15)*8 + (k&7)   [ushort units]
// so a wave's A-fragment load (16 rows x 32 k) is one contiguous 1KB chunk.
__global__ __launch_bounds__(256) void k_pre3(const float* __restrict__ in,
                                              const float* __restrict__ scaleWH,
                                              const float* __restrict__ SU,
                                              unsigned short* __restrict__ xt) {
    __shared__ float lds[8224];
    const int r = blockIdx.x, t = threadIdx.x;
    float v[32];
    const float4* xp = reinterpret_cast<const float4*>(in + (size_t)r * IN_F);
    const float4* sp = reinterpret_cast<const float4*>(scaleWH);
    const float4* up = reinterpret_cast<const float4*>(SU);
#pragma unroll
    for (int q = 0; q < 8; ++q) {
        float4 x = xp[t * 8 + q], s = sp[t * 8 + q], u = up[t * 8 + q];
        v[q * 4 + 0] = x.x / s.x * u.x;
        v[q * 4 + 1] = x.y / s.y * u.y;
        v[q * 4 + 2] = x.z / s.z * u.z;
        v[q * 4 + 3] = x.w / s.w * u.w;
    }
    fwht8192(v, lds, t);
    // thread t holds k = t*32 + j; write 4 x 16B chunks (lk8 = j>>3)
    const size_t base = ((size_t)(r >> 4) * 256 + t) * 512 + (r & 15) * 8;
#pragma unroll
    for (int q = 0; q < 4; ++q) {
        unsigned int w[4];
#pragma unroll
        for (int p = 0; p < 4; ++p) {
            unsigned int lo = f2bf(v[q * 8 + 2 * p]     * FWHT_SCALE);
            unsigned int hi = f2bf(v[q * 8 + 2 * p + 1] * FWHT_SCALE);
            w[p] = lo | (hi << 16);
        }
        *reinterpret_cast<uint4*>(xt + base + q * 128) = make_uint4(w[0], w[1], w[2], w[3]);
    }
}

// ---- Kernel B: barrier-free GEMM; tiled-contiguous A loads; deep Q prefetch -
// grid (128, NSL); 256 thr = 4 waves (2x2); block tile 128x64; K-step 32.
// A: reg ping-pong depth 2 (contiguous 1KB wave loads from tiled xt).
// Qidxs: scalar dword loads prefetched 4 iterations ahead.
__global__ __launch_bounds__(256, 4) void k_gemm4(
        const unsigned short* __restrict__ xt,
        const int* __restrict__ Qidxs,
        const float* __restrict__ cb,
        const float* __restrict__ wscale,
        unsigned short* __restrict__ pout) {
    __shared__ __align__(16) unsigned short cbl[CB][8];
    const int tid = threadIdx.x;
    const int wave = tid >> 6, lane = tid & 63;
    const int wr = wave >> 1, wc = wave & 1;
    const int lr = lane & 15, lk8 = lane >> 4;
    const int n0 = blockIdx.x * NTB;
    const int ks0 = blockIdx.y * KSLICE;
    const int ksb = ks0 >> 5;           // k-block index of slice start
    const int QC = IN_F / 8;

    const float wsc = wscale[0];
    for (int e = tid; e < CB * 8; e += 256) cbl[e >> 3][e & 7] = f2bf(cb[e] * wsc);

    f32x4 acc[4][2];
#pragma unroll
    for (int mt = 0; mt < 4; ++mt)
#pragma unroll
        for (int nt = 0; nt < 2; ++nt) acc[mt][nt] = (f32x4){0.f, 0.f, 0.f, 0.f};

    // wave-local tiled A base: rowgrp = wr*4 + mt, kblk = ksb + it
    const unsigned short* xw = xt + ((size_t)(wr * 4) * 256 + ksb) * 512 + lane * 8;
    const int* q0 = Qidxs + (size_t)(n0 + wc * 32 + lr) * QC + ks0 / 8;

#define LOADA(dst, it)                                                        \
    {                                                                         \
        _Pragma("unroll")                                                     \
        for (int mt = 0; mt < 4; ++mt)                                        \
            dst[mt] = *reinterpret_cast<const bf8*>(xw + ((size_t)mt * 256 + (it)) * 512); \
    }
#define LOADI(d, it)                                                          \
    { d[0] = q0[(it) * 4 + lk8]; d[1] = q0[16 * QC + (it) * 4 + lk8]; }
#define COMPUTE(A_, q_)                                                       \
    {                                                                         \
        bf8 b0 = *(const bf8*)&cbl[q_[0]][0];                                 \
        bf8 b1 = *(const bf8*)&cbl[q_[1]][0];                                 \
        _Pragma("unroll")                                                     \
        for (int mt = 0; mt < 4; ++mt) {                                      \
            acc[mt][0] = __builtin_amdgcn_mfma_f32_16x16x32_bf16(A_[mt], b0, acc[mt][0], 0, 0, 0); \
            acc[mt][1] = __builtin_amdgcn_mfma_f32_16x16x32_bf16(A_[mt], b1, acc[mt][1], 0, 0, 0); \
        }                                                                     \
    }

    bf8 Aa[4], Ab[4];
    int qA[2], qB[2], qC[2], qD[2];
    LOADA(Aa, 0) LOADA(Ab, 1)
    LOADI(qA, 0) LOADI(qB, 1) LOADI(qC, 2) LOADI(qD, 3)
    __syncthreads();   // cbl ready

#pragma unroll 1
    for (int it = 0; it < NIT; it += 2) {
        bf8 An[4], Am[4];
        int qn[2] = {0, 0}, qm[2] = {0, 0};
        const bool moreA = (it + 2) < NIT;
        const bool moreQ = (it + 4) < NIT;
        if (moreA) { LOADA(An, it + 2) LOADA(Am, it + 3) }
        if (moreQ) { LOADI(qn, it + 4) LOADI(qm, it + 5) }
        COMPUTE(Aa, qA)
        COMPUTE(Ab, qB)
        if (moreA) {
#pragma unroll
            for (int mt = 0; mt < 4; ++mt) { Aa[mt] = An[mt]; Ab[mt] = Am[mt]; }
            qA[0] = qC[0]; qA[1] = qC[1]; qB[0] = qD[0]; qB[1] = qD[1];
            qC[0] = qn[0]; qC[1] = qn[1]; qD[0] = qm[0]; qD[1] = qm[1];
        }
    }
#undef LOADA
#undef LOADI
#undef COMPUTE

    // epilogue: C/D col=lane&15, row=(lane>>4)*4+reg; bf16 partial store
    unsigned short* ps = pout + (size_t)blockIdx.y * (NROWS * OUT_F);
#pragma unroll
    for (int mt = 0; mt < 4; ++mt) {
        const int row = wr * 64 + mt * 16 + lk8 * 4;
#pragma unroll
        for (int nt = 0; nt < 2; ++nt) {
            const int col = n0 + wc * 32 + nt * 16 + lr;
#pragma unroll
            for (int r2 = 0; r2 < 4; ++r2)
                ps[(size_t)(row + r2) * OUT_F + col] = f2bf(acc[mt][nt][r2]);
        }
    }
}

// ---- Kernel C: out = fwht(sum_slices)*SV + bias  [f32 out] ----
__global__ __launch_bounds__(256) void k_post2(const unsigned short* __restrict__ pin,
                                               const float* __restrict__ SV,
                                               const float* __restrict__ bias,
                                               float* __restrict__ out) {
    __shared__ float lds[8224];
    const int r = blockIdx.x, t = threadIdx.x;
    float v[32];
#pragma unroll
    for (int j = 0; j < 32; ++j) v[j] = 0.f;
#pragma unroll 1
    for (int sl = 0; sl < NSL; ++sl) {
        const uint4* p = reinterpret_cast<const uint4*>(
            pin + (size_t)sl * NROWS * OUT_F + (size_t)r * OUT_F + t * 32);
#pragma unroll
        for (int q = 0; q < 4; ++q) {
            float a[8];
            unpack8(p[q], a);
#pragma unroll
            for (int j = 0; j < 8; ++j) v[q * 8 + j] += a[j];
        }
    }
    fwht8192(v, lds, t);
    const float4* svp = reinterpret_cast<const float4*>(SV);
    const float4* bip = reinterpret_cast<const float4*>(bias);
    float4* op = reinterpret_cast<float4*>(out + (size_t)r * OUT_F);
#pragma unroll
    for (int q = 0; q < 8; ++q) {
        float4 sv = svp[t * 8 + q], bi = bip[t * 8 + q], o;
        o.x = v[q * 4 + 0] * FWHT_SCALE * sv.x + bi.x;
        o.y = v[q * 4 + 1] * FWHT_SCALE * sv.y + bi.y;
        o.z = v[q * 4 + 2] * FWHT_SCALE * sv.z + bi.z;
        o.w = v[q * 4 + 3] * FWHT_SCALE * sv.w + bi.w;
        op[t * 8 + q] = o;
    }
}

extern "C" void kernel_launch(void* const* d_in, const int* in_sizes, int n_in,
                              void* d_out, int out_size, void* d_ws, size_t ws_size,
                              hipStream_t stream) {
    const float* in      = (const float*)d_in[0];
    const int*   Qidxs   = (const int*)d_in[1];
    const float* cb      = (const float*)d_in[2];
    const float* scaleWH = (const float*)d_in[3];
    const float* SU      = (const float*)d_in[4];
    const float* SV      = (const float*)d_in[5];
    const float* wscale  = (const float*)d_in[6];
    const float* bias    = (const float*)d_in[7];
    float* out = (float*)d_out;

    unsigned short* xt    = (unsigned short*)d_ws;                    // 2 MB (tiled)
    unsigned short* parts = (unsigned short*)((char*)d_ws
                            + (size_t)NROWS * IN_F * 2);              // 16 MB

    k_pre3<<<NROWS, 256, 0, stream>>>(in, scaleWH, SU, xt);
    k_gemm4<<<dim3(OUT_F / NTB, NSL), 256, 0, stream>>>(xt, Qidxs, cb, wscale, parts);
    k_post2<<<NROWS, 256, 0, stream>>>(parts, SV, bias, out);
}